// Round 1
// baseline (328.086 us; speedup 1.0000x reference)
//
#include <hip/hip_runtime.h>
#include <hip/hip_bf16.h>

typedef __bf16 bf16_t;
typedef bf16_t bf16x8 __attribute__((ext_vector_type(8)));
typedef bf16_t bf16x4 __attribute__((ext_vector_type(4)));
typedef float  f32x4  __attribute__((ext_vector_type(4)));

#define LDC 104   // padded stride (bf16 elems) for 96-wide tiles
#define LDT 72    // padded stride for 64-wide tiles

// ws layout (bytes)
#define WS_WQ    0
#define WS_WK    19968
#define WS_WV    39936
#define WS_WP    59904
#define WS_FC1   79872      // [384][104] bf16
#define WS_FC2   159744     // [4][96][104] bf16 (chunked over inner dim)
#define WS_BIAS  239616     // [3][64][64] f32 : 16*sigmoid(cpb bias)

__device__ __forceinline__ f32x4 mfma16(bf16x8 a, bf16x8 b, f32x4 c) {
    return __builtin_amdgcn_mfma_f32_16x16x32_bf16(a, b, c, 0, 0, 0);
}

__device__ __forceinline__ float cpbf(int v) {   // v in -7..7
    float x = (float)v * (8.0f / 7.0f);
    float l = log2f(fabsf(x) + 1.0f) * (1.0f / 3.0f);
    return x < 0.f ? -l : l;
}

__device__ __forceinline__ int regcnt(int t, int hw, int ww) {
    int r = t >> 3, c = t & 7;
    int rr = (hw == 31) ? (r < 4 ? 1 : 2) : 0;
    int cc = (ww == 31) ? (c < 4 ? 1 : 2) : 0;
    return rr * 3 + cc;
}

// ---------------- Kernel 0: CPB table + weight repack (bf16, transposed, padded) ----------------
__global__ __launch_bounds__(256) void k0_prep(
    const float* __restrict__ qw, const float* __restrict__ kw,
    const float* __restrict__ vw, const float* __restrict__ pw,
    const float* __restrict__ fc1w, const float* __restrict__ fc2w,
    const float* __restrict__ cw1, const float* __restrict__ cb1,
    const float* __restrict__ cw2, char* __restrict__ ws)
{
    int tid = threadIdx.x;
    if (blockIdx.x == 0) {
        __shared__ float table[225 * 3];
        if (tid < 225) {
            int ia = tid / 15, ib = tid % 15;
            float c0 = cpbf(ia - 7), c1 = cpbf(ib - 7);
            float a0 = 0.f, a1 = 0.f, a2 = 0.f;
            for (int j = 0; j < 512; ++j) {
                float h = fmaf(c0, cw1[j], fmaf(c1, cw1[512 + j], cb1[j]));
                h = fmaxf(h, 0.f);
                a0 = fmaf(h, cw2[j * 3 + 0], a0);
                a1 = fmaf(h, cw2[j * 3 + 1], a1);
                a2 = fmaf(h, cw2[j * 3 + 2], a2);
            }
            table[tid * 3 + 0] = a0; table[tid * 3 + 1] = a1; table[tid * 3 + 2] = a2;
        }
        __syncthreads();
        float* bias = (float*)(ws + WS_BIAS);
        for (int e = tid; e < 3 * 64 * 64; e += 256) {
            int h = e >> 12, nm = e & 4095, n = nm >> 6, m = nm & 63;
            int dr = (n >> 3) - (m >> 3) + 7, dc = (n & 7) - (m & 7) + 7;
            float t = table[(dr * 15 + dc) * 3 + h];
            bias[e] = 16.f / (1.f + __expf(-t));
        }
    } else {
        int idx = (blockIdx.x - 1) * 256 + tid;
        if (idx < 36864) {                       // q,k,v,proj: [96 in][96 out] -> [out][in]
            int which = idx / 9216, r = idx % 9216;
            int o = r / 96, i = r % 96;
            const float* src = which == 0 ? qw : which == 1 ? kw : which == 2 ? vw : pw;
            ((bf16_t*)(ws + WS_WQ + which * 19968))[o * LDC + i] = (bf16_t)src[i * 96 + o];
        } else if (idx < 73728) {                // fc1: [96][384] -> [384][96]
            int r = idx - 36864;
            int o = r / 96, i = r % 96;
            ((bf16_t*)(ws + WS_FC1))[o * LDC + i] = (bf16_t)fc1w[i * 384 + o];
        } else if (idx < 110592) {               // fc2: [384][96] -> [4][96 out][96 in-chunk]
            int r = idx - 73728;
            int ks = r / 9216, rr = r % 9216, o = rr / 96, j = rr % 96;
            ((bf16_t*)(ws + WS_FC2))[(ks * 96 + o) * LDC + j] = (bf16_t)fc2w[(ks * 96 + j) * 96 + o];
        }
    }
}

// ---------------- Kernel A: fused window attention -> hs (into d_out) ----------------
__global__ __launch_bounds__(256) void kA_attn(
    const float* __restrict__ hidden, const float* __restrict__ tv,
    const float* __restrict__ qb, const float* __restrict__ vb,
    const float* __restrict__ pb, const float* __restrict__ lsc,
    const float* __restrict__ lnww, const float* __restrict__ lnwb,
    const float* __restrict__ lnbw, const float* __restrict__ lnbb,
    const char* __restrict__ ws, float* __restrict__ hs)
{
    __shared__ __align__(16) char sm[73728];
    bf16_t* xwb   = (bf16_t*)(sm + 0);        // [64][104]
    bf16_t* wbuf  = (bf16_t*)(sm + 13312);    // [96][104]
    bf16_t* qn    = (bf16_t*)(sm + 33280);    // [64][104]
    bf16_t* kn    = (bf16_t*)(sm + 46592);    // [64][104]
    bf16_t* vT    = (bf16_t*)(sm + 59904);    // [96][72]
    bf16_t* P     = (bf16_t*)(sm + 0);        // [3][64][72] overlays xwb+wbuf
    bf16_t* ctxb  = (bf16_t*)(sm + 33280);    // overlays qn
    bf16_t* wbuf2 = (bf16_t*)(sm + 46592);    // overlays kn(+vT head)

    const int tid = threadIdx.x;
    const int wv = tid >> 6, lane = tid & 63, lg = lane >> 4, lr = lane & 15;
    const int wid = blockIdx.x;
    const int bat = wid >> 10, wim = wid & 1023, hw = wim >> 5, wwi = wim & 31;

    // phase 1: gather rolled window + Wq
    #pragma unroll
    for (int i = 0; i < 6; ++i) {
        int idx = tid + 256 * i;
        int t = idx / 24, grp = idx % 24;
        int gr = ((hw << 3) + (t >> 3) + 4) & 255;
        int gc = ((wwi << 3) + (t & 7) + 4) & 255;
        const float4 v = *(const float4*)(hidden + (((size_t)bat << 16) + (gr << 8) + gc) * 96 + grp * 4);
        bf16x4 p; p[0] = (bf16_t)v.x; p[1] = (bf16_t)v.y; p[2] = (bf16_t)v.z; p[3] = (bf16_t)v.w;
        *(bf16x4*)(xwb + t * LDC + grp * 4) = p;
    }
    {
        const float4* s4 = (const float4*)(ws + WS_WQ);
        float4* d4 = (float4*)wbuf;
        for (int i = tid; i < 1248; i += 256) d4[i] = s4[i];
    }
    __syncthreads();

    // ---- Q ----
    {
        bf16x8 af[3];
        #pragma unroll
        for (int ks = 0; ks < 3; ++ks) af[ks] = *(const bf16x8*)(xwb + (16 * wv + lr) * LDC + 32 * ks + 8 * lg);
        f32x4 acc[6];
        #pragma unroll
        for (int nt = 0; nt < 6; ++nt) {
            f32x4 a = {0.f, 0.f, 0.f, 0.f};
            #pragma unroll
            for (int ks = 0; ks < 3; ++ks)
                a = mfma16(af[ks], *(const bf16x8*)(wbuf + (16 * nt + lr) * LDC + 32 * ks + 8 * lg), a);
            float bq = qb[16 * nt + lr];
            #pragma unroll
            for (int j = 0; j < 4; ++j) a[j] += bq;
            acc[nt] = a;
        }
        #pragma unroll
        for (int h = 0; h < 3; ++h) {
            #pragma unroll
            for (int j = 0; j < 4; ++j) {
                float s = acc[2 * h][j] * acc[2 * h][j] + acc[2 * h + 1][j] * acc[2 * h + 1][j];
                s += __shfl_xor(s, 1); s += __shfl_xor(s, 2); s += __shfl_xor(s, 4); s += __shfl_xor(s, 8);
                float inv = 1.f / fmaxf(sqrtf(s), 1e-12f);
                int row = 16 * wv + 4 * lg + j;
                qn[row * LDC + 32 * h + lr]      = (bf16_t)(acc[2 * h][j] * inv);
                qn[row * LDC + 32 * h + 16 + lr] = (bf16_t)(acc[2 * h + 1][j] * inv);
            }
        }
    }
    __syncthreads();
    { const float4* s4 = (const float4*)(ws + WS_WK); float4* d4 = (float4*)wbuf;
      for (int i = tid; i < 1248; i += 256) d4[i] = s4[i]; }
    __syncthreads();

    // ---- K ----
    {
        bf16x8 af[3];
        #pragma unroll
        for (int ks = 0; ks < 3; ++ks) af[ks] = *(const bf16x8*)(xwb + (16 * wv + lr) * LDC + 32 * ks + 8 * lg);
        f32x4 acc[6];
        #pragma unroll
        for (int nt = 0; nt < 6; ++nt) {
            f32x4 a = {0.f, 0.f, 0.f, 0.f};
            #pragma unroll
            for (int ks = 0; ks < 3; ++ks)
                a = mfma16(af[ks], *(const bf16x8*)(wbuf + (16 * nt + lr) * LDC + 32 * ks + 8 * lg), a);
            acc[nt] = a;
        }
        #pragma unroll
        for (int h = 0; h < 3; ++h) {
            #pragma unroll
            for (int j = 0; j < 4; ++j) {
                float s = acc[2 * h][j] * acc[2 * h][j] + acc[2 * h + 1][j] * acc[2 * h + 1][j];
                s += __shfl_xor(s, 1); s += __shfl_xor(s, 2); s += __shfl_xor(s, 4); s += __shfl_xor(s, 8);
                float inv = 1.f / fmaxf(sqrtf(s), 1e-12f);
                int row = 16 * wv + 4 * lg + j;
                kn[row * LDC + 32 * h + lr]      = (bf16_t)(acc[2 * h][j] * inv);
                kn[row * LDC + 32 * h + 16 + lr] = (bf16_t)(acc[2 * h + 1][j] * inv);
            }
        }
    }
    __syncthreads();
    { const float4* s4 = (const float4*)(ws + WS_WV); float4* d4 = (float4*)wbuf;
      for (int i = tid; i < 1248; i += 256) d4[i] = s4[i]; }
    __syncthreads();

    // ---- V (store transposed) ----
    {
        bf16x8 af[3];
        #pragma unroll
        for (int ks = 0; ks < 3; ++ks) af[ks] = *(const bf16x8*)(xwb + (16 * wv + lr) * LDC + 32 * ks + 8 * lg);
        #pragma unroll
        for (int nt = 0; nt < 6; ++nt) {
            f32x4 a = {0.f, 0.f, 0.f, 0.f};
            #pragma unroll
            for (int ks = 0; ks < 3; ++ks)
                a = mfma16(af[ks], *(const bf16x8*)(wbuf + (16 * nt + lr) * LDC + 32 * ks + 8 * lg), a);
            int col = 16 * nt + lr;
            float bv = vb[col];
            bf16x4 pk;
            #pragma unroll
            for (int j = 0; j < 4; ++j) pk[j] = (bf16_t)(a[j] + bv);
            *(bf16x4*)(vT + col * LDT + 16 * wv + 4 * lg) = pk;
        }
    }
    __syncthreads();

    // ---- S = qn@kn^T, softmax, P ----
    {
        float ls[3];
        #pragma unroll
        for (int h = 0; h < 3; ++h) ls[h] = __expf(fminf(lsc[h], 4.6051702f));
        f32x4 s[3][4];
        #pragma unroll
        for (int h = 0; h < 3; ++h) {
            bf16x8 aq = *(const bf16x8*)(qn + (16 * wv + lr) * LDC + 32 * h + 8 * lg);
            #pragma unroll
            for (int f = 0; f < 4; ++f) {
                f32x4 z = {0.f, 0.f, 0.f, 0.f};
                s[h][f] = mfma16(aq, *(const bf16x8*)(kn + (16 * f + lr) * LDC + 32 * h + 8 * lg), z);
            }
        }
        const float* biasT = (const float*)(ws + WS_BIAS);
        int cntm[4], cnti[4];
        #pragma unroll
        for (int f = 0; f < 4; ++f) cntm[f] = regcnt(16 * f + lr, hw, wwi);
        #pragma unroll
        for (int j = 0; j < 4; ++j) cnti[j] = regcnt(16 * wv + 4 * lg + j, hw, wwi);
        #pragma unroll
        for (int h = 0; h < 3; ++h) {
            #pragma unroll
            for (int f = 0; f < 4; ++f) {
                #pragma unroll
                for (int j = 0; j < 4; ++j) {
                    float b = biasT[(h << 12) + (16 * wv + 4 * lg + j) * 64 + 16 * f + lr];
                    float mk = (cnti[j] != cntm[f]) ? -100.f : 0.f;
                    s[h][f][j] = fmaf(s[h][f][j], ls[h], b + mk);
                }
            }
            #pragma unroll
            for (int j = 0; j < 4; ++j) {
                float mx = fmaxf(fmaxf(s[h][0][j], s[h][1][j]), fmaxf(s[h][2][j], s[h][3][j]));
                mx = fmaxf(mx, __shfl_xor(mx, 1)); mx = fmaxf(mx, __shfl_xor(mx, 2));
                mx = fmaxf(mx, __shfl_xor(mx, 4)); mx = fmaxf(mx, __shfl_xor(mx, 8));
                float sum = 0.f;
                #pragma unroll
                for (int f = 0; f < 4; ++f) { float e = __expf(s[h][f][j] - mx); s[h][f][j] = e; sum += e; }
                sum += __shfl_xor(sum, 1); sum += __shfl_xor(sum, 2); sum += __shfl_xor(sum, 4); sum += __shfl_xor(sum, 8);
                float inv = 1.f / sum;
                int row = 16 * wv + 4 * lg + j;
                #pragma unroll
                for (int f = 0; f < 4; ++f)
                    P[h * 64 * LDT + row * LDT + 16 * f + lr] = (bf16_t)(s[h][f][j] * inv);
            }
        }
    }
    __syncthreads();

    // ---- ctx = P@V ----
    {
        f32x4 ctx[6]; f32x4 zz = {0.f, 0.f, 0.f, 0.f};
        #pragma unroll
        for (int t = 0; t < 6; ++t) ctx[t] = zz;
        #pragma unroll
        for (int h = 0; h < 3; ++h) {
            #pragma unroll
            for (int ks = 0; ks < 2; ++ks) {
                bf16x8 ap = *(const bf16x8*)(P + h * 64 * LDT + (16 * wv + lr) * LDT + 32 * ks + 8 * lg);
                #pragma unroll
                for (int dt = 0; dt < 2; ++dt)
                    ctx[2 * h + dt] = mfma16(ap, *(const bf16x8*)(vT + (32 * h + 16 * dt + lr) * LDT + 32 * ks + 8 * lg), ctx[2 * h + dt]);
            }
        }
        #pragma unroll
        for (int t = 0; t < 6; ++t) {
            #pragma unroll
            for (int j = 0; j < 4; ++j)
                ctxb[(16 * wv + 4 * lg + j) * LDC + 16 * t + lr] = (bf16_t)ctx[t][j];
        }
    }
    __syncthreads();
    { const float4* s4 = (const float4*)(ws + WS_WP); float4* d4 = (float4*)wbuf2;
      for (int i = tid; i < 1248; i += 256) d4[i] = s4[i]; }
    __syncthreads();

    // ---- proj + conditional LN + residual -> hs ----
    {
        bf16x8 af[3];
        #pragma unroll
        for (int ks = 0; ks < 3; ++ks) af[ks] = *(const bf16x8*)(ctxb + (16 * wv + lr) * LDC + 32 * ks + 8 * lg);
        f32x4 acc[6];
        #pragma unroll
        for (int nt = 0; nt < 6; ++nt) {
            f32x4 a = {0.f, 0.f, 0.f, 0.f};
            #pragma unroll
            for (int ks = 0; ks < 3; ++ks)
                a = mfma16(af[ks], *(const bf16x8*)(wbuf2 + (16 * nt + lr) * LDC + 32 * ks + 8 * lg), a);
            float bp = pb[16 * nt + lr];
            #pragma unroll
            for (int j = 0; j < 4; ++j) a[j] += bp;
            acc[nt] = a;
        }
        float tb = tv[bat];
        #pragma unroll
        for (int j = 0; j < 4; ++j) {
            float smn = 0.f, sq = 0.f;
            #pragma unroll
            for (int t = 0; t < 6; ++t) { float v = acc[t][j]; smn += v; sq = fmaf(v, v, sq); }
            smn += __shfl_xor(smn, 1); smn += __shfl_xor(smn, 2); smn += __shfl_xor(smn, 4); smn += __shfl_xor(smn, 8);
            sq  += __shfl_xor(sq, 1);  sq  += __shfl_xor(sq, 2);  sq  += __shfl_xor(sq, 4);  sq  += __shfl_xor(sq, 8);
            float mean = smn * (1.f / 96.f);
            float var  = sq * (1.f / 96.f) - mean * mean;
            float rstd = rsqrtf(var + 1e-5f);
            int trow = 16 * wv + 4 * lg + j;
            int gr = ((hw << 3) + (trow >> 3) + 4) & 255;
            int gc = ((wwi << 3) + (trow & 7) + 4) & 255;
            size_t gbase = (((size_t)bat << 16) + (gr << 8) + gc) * 96;
            #pragma unroll
            for (int t = 0; t < 6; ++t) {
                int col = 16 * t + lr;
                float w = fmaf(tb, lnww[col], lnwb[col]);
                float b = fmaf(tb, lnbw[col], lnbb[col]);
                float xn = (acc[t][j] - mean) * rstd;
                hs[gbase + col] = hidden[gbase + col] + fmaf(w, xn, b);
            }
        }
    }
}

// ---------------- Kernel B: MLP + conditional LN + residual (in-place on d_out) ----------------
__global__ __launch_bounds__(256) void kB_mlp(
    const float* __restrict__ tv, const float* __restrict__ fc1b,
    const float* __restrict__ fc2b,
    const float* __restrict__ lnww, const float* __restrict__ lnwb,
    const float* __restrict__ lnbw, const float* __restrict__ lnbb,
    const char* __restrict__ ws, float* __restrict__ io)
{
    __shared__ __align__(16) char sm[66560];
    bf16_t* hsb  = (bf16_t*)(sm + 0);        // [64][104]
    bf16_t* w1c  = (bf16_t*)(sm + 13312);    // [96][104]
    bf16_t* gbuf = (bf16_t*)(sm + 33280);    // [64][104]
    bf16_t* w2c  = (bf16_t*)(sm + 46592);    // [96][104]

    const int tid = threadIdx.x;
    const int wv = tid >> 6, lane = tid & 63, lg = lane >> 4, lr = lane & 15;
    const size_t t0 = (size_t)blockIdx.x * 64;

    #pragma unroll
    for (int i = 0; i < 6; ++i) {
        int idx = tid + 256 * i;
        int t = idx / 24, grp = idx % 24;
        const float4 v = *(const float4*)(io + (t0 + t) * 96 + grp * 4);
        bf16x4 p; p[0] = (bf16_t)v.x; p[1] = (bf16_t)v.y; p[2] = (bf16_t)v.z; p[3] = (bf16_t)v.w;
        *(bf16x4*)(hsb + t * LDC + grp * 4) = p;
    }
    __syncthreads();

    f32x4 mlp[6]; f32x4 zz = {0.f, 0.f, 0.f, 0.f};
    #pragma unroll
    for (int t = 0; t < 6; ++t) mlp[t] = zz;
    bf16x8 hf[3];
    #pragma unroll
    for (int ks = 0; ks < 3; ++ks) hf[ks] = *(const bf16x8*)(hsb + (16 * wv + lr) * LDC + 32 * ks + 8 * lg);

    for (int ch = 0; ch < 4; ++ch) {
        { const float4* s1 = (const float4*)(ws + WS_FC1 + ch * 19968);
          const float4* s2 = (const float4*)(ws + WS_FC2 + ch * 19968);
          float4* d1 = (float4*)w1c; float4* d2 = (float4*)w2c;
          for (int i = tid; i < 1248; i += 256) { d1[i] = s1[i]; d2[i] = s2[i]; } }
        __syncthreads();
        #pragma unroll
        for (int nt = 0; nt < 6; ++nt) {
            f32x4 a = {0.f, 0.f, 0.f, 0.f};
            #pragma unroll
            for (int ks = 0; ks < 3; ++ks)
                a = mfma16(hf[ks], *(const bf16x8*)(w1c + (16 * nt + lr) * LDC + 32 * ks + 8 * lg), a);
            float bb = fc1b[ch * 96 + 16 * nt + lr];
            #pragma unroll
            for (int j = 0; j < 4; ++j) {
                float x = a[j] + bb;
                float g = 0.5f * x * (1.f + erff(x * 0.70710678f));
                gbuf[(16 * wv + 4 * lg + j) * LDC + 16 * nt + lr] = (bf16_t)g;
            }
        }
        __syncthreads();
        #pragma unroll
        for (int ks = 0; ks < 3; ++ks) {
            bf16x8 gf = *(const bf16x8*)(gbuf + (16 * wv + lr) * LDC + 32 * ks + 8 * lg);
            #pragma unroll
            for (int nt = 0; nt < 6; ++nt)
                mlp[nt] = mfma16(gf, *(const bf16x8*)(w2c + (16 * nt + lr) * LDC + 32 * ks + 8 * lg), mlp[nt]);
        }
        __syncthreads();
    }

    float tb = tv[t0 >> 16];
    #pragma unroll
    for (int nt = 0; nt < 6; ++nt) {
        float bb = fc2b[16 * nt + lr];
        #pragma unroll
        for (int j = 0; j < 4; ++j) mlp[nt][j] += bb;
    }
    #pragma unroll
    for (int j = 0; j < 4; ++j) {
        float smn = 0.f, sq = 0.f;
        #pragma unroll
        for (int t = 0; t < 6; ++t) { float v = mlp[t][j]; smn += v; sq = fmaf(v, v, sq); }
        smn += __shfl_xor(smn, 1); smn += __shfl_xor(smn, 2); smn += __shfl_xor(smn, 4); smn += __shfl_xor(smn, 8);
        sq  += __shfl_xor(sq, 1);  sq  += __shfl_xor(sq, 2);  sq  += __shfl_xor(sq, 4);  sq  += __shfl_xor(sq, 8);
        float mean = smn * (1.f / 96.f);
        float var  = sq * (1.f / 96.f) - mean * mean;
        float rstd = rsqrtf(var + 1e-5f);
        size_t row = t0 + 16 * wv + 4 * lg + j;
        #pragma unroll
        for (int t = 0; t < 6; ++t) {
            int col = 16 * t + lr;
            float w = fmaf(tb, lnww[col], lnwb[col]);
            float b = fmaf(tb, lnbw[col], lnbb[col]);
            float xn = (mlp[t][j] - mean) * rstd;
            io[row * 96 + col] = io[row * 96 + col] + fmaf(w, xn, b);
        }
    }
}

extern "C" void kernel_launch(void* const* d_in, const int* in_sizes, int n_in,
                              void* d_out, int out_size, void* d_ws, size_t ws_size,
                              hipStream_t stream)
{
    const float* hidden = (const float*)d_in[0];
    const float* tv     = (const float*)d_in[1];
    const float* q_w    = (const float*)d_in[2];
    const float* q_b    = (const float*)d_in[3];
    const float* k_w    = (const float*)d_in[4];
    const float* v_w    = (const float*)d_in[5];
    const float* v_b    = (const float*)d_in[6];
    const float* p_w    = (const float*)d_in[7];
    const float* p_b    = (const float*)d_in[8];
    const float* lsc    = (const float*)d_in[9];
    const float* cw1    = (const float*)d_in[10];
    const float* cb1    = (const float*)d_in[11];
    const float* cw2    = (const float*)d_in[12];
    const float* lnb_ww = (const float*)d_in[13];
    const float* lnb_wb = (const float*)d_in[14];
    const float* lnb_bw = (const float*)d_in[15];
    const float* lnb_bb = (const float*)d_in[16];
    const float* lna_ww = (const float*)d_in[17];
    const float* lna_wb = (const float*)d_in[18];
    const float* lna_bw = (const float*)d_in[19];
    const float* lna_bb = (const float*)d_in[20];
    const float* fc1_w  = (const float*)d_in[21];
    const float* fc1_b  = (const float*)d_in[22];
    const float* fc2_w  = (const float*)d_in[23];
    const float* fc2_b  = (const float*)d_in[24];
    char* ws = (char*)d_ws;
    float* out = (float*)d_out;

    k0_prep<<<dim3(433), dim3(256), 0, stream>>>(q_w, k_w, v_w, p_w, fc1_w, fc2_w, cw1, cb1, cw2, ws);
    kA_attn<<<dim3(2048), dim3(256), 0, stream>>>(hidden, tv, q_b, v_b, p_b, lsc,
                                                  lnb_ww, lnb_wb, lnb_bw, lnb_bb, ws, out);
    kB_mlp<<<dim3(2048), dim3(256), 0, stream>>>(tv, fc1_b, fc2_b,
                                                 lna_ww, lna_wb, lna_bw, lna_bb, ws, out);
}

// Round 2
// 326.647 us; speedup vs baseline: 1.0044x; 1.0044x over previous
//
#include <hip/hip_runtime.h>
#include <hip/hip_bf16.h>

typedef __bf16 bf16_t;
typedef bf16_t bf16x8 __attribute__((ext_vector_type(8)));
typedef bf16_t bf16x4 __attribute__((ext_vector_type(4)));
typedef float  f32x4  __attribute__((ext_vector_type(4)));

#define LDC 104   // padded stride (bf16 elems) for 96-wide tiles
#define LDT 72    // padded stride for 64-wide token-dim tiles

// ws layout (bytes)
#define WS_WQ    0
#define WS_WK    19968
#define WS_WV    39936
#define WS_WP    59904
#define WS_FC1   79872      // [384][104] bf16
#define WS_FC2   159744     // [4][96][104] bf16 (chunked over inner dim)
#define WS_BIAS  239616     // [3][64][64] f32 : 16*sigmoid(cpb bias)

__device__ __forceinline__ f32x4 mfma16(bf16x8 a, bf16x8 b, f32x4 c) {
    return __builtin_amdgcn_mfma_f32_16x16x32_bf16(a, b, c, 0, 0, 0);
}

__device__ __forceinline__ float cpbf(int v) {   // v in -7..7
    float x = (float)v * (8.0f / 7.0f);
    float l = log2f(fabsf(x) + 1.0f) * (1.0f / 3.0f);
    return x < 0.f ? -l : l;
}

__device__ __forceinline__ int regcnt(int t, int hw, int ww) {
    int r = t >> 3, c = t & 7;
    int rr = (hw == 31) ? (r < 4 ? 1 : 2) : 0;
    int cc = (ww == 31) ? (c < 4 ? 1 : 2) : 0;
    return rr * 3 + cc;
}

// ---------------- Kernel 0: CPB table + weight repack (bf16, transposed, padded) ----------------
__global__ __launch_bounds__(512) void k0_prep(
    const float* __restrict__ qw, const float* __restrict__ kw,
    const float* __restrict__ vw, const float* __restrict__ pw,
    const float* __restrict__ fc1w, const float* __restrict__ fc2w,
    const float* __restrict__ cw1, const float* __restrict__ cb1,
    const float* __restrict__ cw2, char* __restrict__ ws)
{
    int tid = threadIdx.x;
    if (blockIdx.x == 0) {
        __shared__ float part[450 * 3];
        __shared__ float table[225 * 3];
        if (tid < 450) {
            int pos = tid >> 1, half = tid & 1;
            int ia = pos / 15, ib = pos % 15;
            float c0 = cpbf(ia - 7), c1 = cpbf(ib - 7);
            float a0 = 0.f, a1 = 0.f, a2 = 0.f;
            int j0 = half * 256;
            for (int j = j0; j < j0 + 256; ++j) {
                float h = fmaf(c0, cw1[j], fmaf(c1, cw1[512 + j], cb1[j]));
                h = fmaxf(h, 0.f);
                a0 = fmaf(h, cw2[j * 3 + 0], a0);
                a1 = fmaf(h, cw2[j * 3 + 1], a1);
                a2 = fmaf(h, cw2[j * 3 + 2], a2);
            }
            part[tid * 3 + 0] = a0; part[tid * 3 + 1] = a1; part[tid * 3 + 2] = a2;
        }
        __syncthreads();
        if (tid < 225) {
            table[tid * 3 + 0] = part[(2 * tid) * 3 + 0] + part[(2 * tid + 1) * 3 + 0];
            table[tid * 3 + 1] = part[(2 * tid) * 3 + 1] + part[(2 * tid + 1) * 3 + 1];
            table[tid * 3 + 2] = part[(2 * tid) * 3 + 2] + part[(2 * tid + 1) * 3 + 2];
        }
        __syncthreads();
        float* bias = (float*)(ws + WS_BIAS);
        for (int e = tid; e < 3 * 64 * 64; e += 512) {
            int h = e >> 12, nm = e & 4095, n = nm >> 6, m = nm & 63;
            int dr = (n >> 3) - (m >> 3) + 7, dc = (n & 7) - (m & 7) + 7;
            float t = table[(dr * 15 + dc) * 3 + h];
            bias[e] = 16.f / (1.f + __expf(-t));
        }
    } else {
        int idx = (blockIdx.x - 1) * 512 + tid;
        if (idx < 36864) {                       // q,k,v,proj: [96 in][96 out] -> [out][in]
            int which = idx / 9216, r = idx % 9216;
            int o = r / 96, i = r % 96;
            const float* src = which == 0 ? qw : which == 1 ? kw : which == 2 ? vw : pw;
            ((bf16_t*)(ws + WS_WQ + which * 19968))[o * LDC + i] = (bf16_t)src[i * 96 + o];
        } else if (idx < 73728) {                // fc1: [96][384] -> [384][96]
            int r = idx - 36864;
            int o = r / 96, i = r % 96;
            ((bf16_t*)(ws + WS_FC1))[o * LDC + i] = (bf16_t)fc1w[i * 384 + o];
        } else if (idx < 110592) {               // fc2: [384][96] -> [4][96 out][96 in-chunk]
            int r = idx - 73728;
            int ks = r / 9216, rr = r % 9216, o = rr / 96, j = rr % 96;
            ((bf16_t*)(ws + WS_FC2))[(ks * 96 + o) * LDC + j] = (bf16_t)fc2w[(ks * 96 + j) * 96 + o];
        }
    }
}

// ---------------- Kernel A: fused window attention -> hs (into d_out) ----------------
// LDS 53760 -> 3 blocks/CU. B-fragments of all GEMMs read directly from global ws (L1/L2).
__global__ __launch_bounds__(256, 3) void kA_attn(
    const float* __restrict__ hidden, const float* __restrict__ tv,
    const float* __restrict__ qb, const float* __restrict__ vb,
    const float* __restrict__ pb, const float* __restrict__ lsc,
    const float* __restrict__ lnww, const float* __restrict__ lnwb,
    const float* __restrict__ lnbw, const float* __restrict__ lnbb,
    const char* __restrict__ ws, float* __restrict__ hs)
{
    __shared__ __align__(16) char sm[53760];
    bf16_t* xwb  = (bf16_t*)(sm + 0);         // [64][104]
    bf16_t* qn   = (bf16_t*)(sm + 13312);     // [64][104]
    bf16_t* kn   = (bf16_t*)(sm + 26624);     // [64][104]
    bf16_t* vT   = (bf16_t*)(sm + 39936);     // [96][72]
    bf16_t* P    = (bf16_t*)(sm + 0);         // [3][64][72] = 27648, overlays xwb+qn+kn head (after read barrier)
    bf16_t* ctxb = (bf16_t*)(sm + 39936);     // [64][104], overlays vT (after read barrier)

    const int tid = threadIdx.x;
    const int wv = tid >> 6, lane = tid & 63, lg = lane >> 4, lr = lane & 15;
    const int wid = blockIdx.x;
    const int bat = wid >> 10, wim = wid & 1023, hw = wim >> 5, wwi = wim & 31;

    // ---- phase 1: gather rolled window -> xwb ----
    #pragma unroll
    for (int i = 0; i < 6; ++i) {
        int idx = tid + 256 * i;
        int t = idx / 24, grp = idx - t * 24;
        int gr = ((hw << 3) + (t >> 3) + 4) & 255;
        int gc = ((wwi << 3) + (t & 7) + 4) & 255;
        const float4 v = *(const float4*)(hidden + (((size_t)bat << 16) + (gr << 8) + gc) * 96 + grp * 4);
        bf16x4 p; p[0] = (bf16_t)v.x; p[1] = (bf16_t)v.y; p[2] = (bf16_t)v.z; p[3] = (bf16_t)v.w;
        *(bf16x4*)(xwb + t * LDC + grp * 4) = p;
    }
    __syncthreads();                                         // B1

    // ---- phase 2: fused QKV (B-frags from global), write qn/kn/vT ----
    {
        bf16x8 af[3];
        #pragma unroll
        for (int ks = 0; ks < 3; ++ks) af[ks] = *(const bf16x8*)(xwb + (16 * wv + lr) * LDC + 32 * ks + 8 * lg);
        const bf16_t* Wq = (const bf16_t*)(ws + WS_WQ);
        const bf16_t* Wk = (const bf16_t*)(ws + WS_WK);
        const bf16_t* Wv = (const bf16_t*)(ws + WS_WV);

        #pragma unroll
        for (int h = 0; h < 3; ++h) {        // Q per head (bias, then cosine-normalize)
            f32x4 a0 = {0.f,0.f,0.f,0.f}, a1 = {0.f,0.f,0.f,0.f};
            #pragma unroll
            for (int ks = 0; ks < 3; ++ks) {
                a0 = mfma16(af[ks], *(const bf16x8*)(Wq + (32 * h + lr) * LDC + 32 * ks + 8 * lg), a0);
                a1 = mfma16(af[ks], *(const bf16x8*)(Wq + (32 * h + 16 + lr) * LDC + 32 * ks + 8 * lg), a1);
            }
            float b0 = qb[32 * h + lr], b1 = qb[32 * h + 16 + lr];
            #pragma unroll
            for (int j = 0; j < 4; ++j) { a0[j] += b0; a1[j] += b1; }
            #pragma unroll
            for (int j = 0; j < 4; ++j) {
                float s = a0[j] * a0[j] + a1[j] * a1[j];
                s += __shfl_xor(s, 1); s += __shfl_xor(s, 2); s += __shfl_xor(s, 4); s += __shfl_xor(s, 8);
                float inv = 1.f / fmaxf(sqrtf(s), 1e-12f);
                int row = 16 * wv + 4 * lg + j;
                qn[row * LDC + 32 * h + lr]      = (bf16_t)(a0[j] * inv);
                qn[row * LDC + 32 * h + 16 + lr] = (bf16_t)(a1[j] * inv);
            }
        }
        #pragma unroll
        for (int h = 0; h < 3; ++h) {        // K per head (no bias, normalize)
            f32x4 a0 = {0.f,0.f,0.f,0.f}, a1 = {0.f,0.f,0.f,0.f};
            #pragma unroll
            for (int ks = 0; ks < 3; ++ks) {
                a0 = mfma16(af[ks], *(const bf16x8*)(Wk + (32 * h + lr) * LDC + 32 * ks + 8 * lg), a0);
                a1 = mfma16(af[ks], *(const bf16x8*)(Wk + (32 * h + 16 + lr) * LDC + 32 * ks + 8 * lg), a1);
            }
            #pragma unroll
            for (int j = 0; j < 4; ++j) {
                float s = a0[j] * a0[j] + a1[j] * a1[j];
                s += __shfl_xor(s, 1); s += __shfl_xor(s, 2); s += __shfl_xor(s, 4); s += __shfl_xor(s, 8);
                float inv = 1.f / fmaxf(sqrtf(s), 1e-12f);
                int row = 16 * wv + 4 * lg + j;
                kn[row * LDC + 32 * h + lr]      = (bf16_t)(a0[j] * inv);
                kn[row * LDC + 32 * h + 16 + lr] = (bf16_t)(a1[j] * inv);
            }
        }
        #pragma unroll
        for (int nt = 0; nt < 6; ++nt) {     // V (+bias), store transposed
            f32x4 a = {0.f,0.f,0.f,0.f};
            #pragma unroll
            for (int ks = 0; ks < 3; ++ks)
                a = mfma16(af[ks], *(const bf16x8*)(Wv + (16 * nt + lr) * LDC + 32 * ks + 8 * lg), a);
            float bv_ = vb[16 * nt + lr];
            bf16x4 pk;
            #pragma unroll
            for (int j = 0; j < 4; ++j) pk[j] = (bf16_t)(a[j] + bv_);
            *(bf16x4*)(vT + (16 * nt + lr) * LDT + 16 * wv + 4 * lg) = pk;
        }
    }
    __syncthreads();                                         // B2

    // ---- phase 3: S = qn@kn^T (+bias+mask), softmax, write P (overlays xwb/qn/kn) ----
    {
        bf16x8 aq[3], bk[3][4];
        #pragma unroll
        for (int h = 0; h < 3; ++h) {
            aq[h] = *(const bf16x8*)(qn + (16 * wv + lr) * LDC + 32 * h + 8 * lg);
            #pragma unroll
            for (int f = 0; f < 4; ++f)
                bk[h][f] = *(const bf16x8*)(kn + (16 * f + lr) * LDC + 32 * h + 8 * lg);
        }
        __syncthreads();                                     // B3: all qn/kn reads done

        float ls[3];
        #pragma unroll
        for (int h = 0; h < 3; ++h) ls[h] = __expf(fminf(lsc[h], 4.6051702f));
        f32x4 s[3][4];
        #pragma unroll
        for (int h = 0; h < 3; ++h)
            #pragma unroll
            for (int f = 0; f < 4; ++f) {
                f32x4 z = {0.f,0.f,0.f,0.f};
                s[h][f] = mfma16(aq[h], bk[h][f], z);
            }
        const float* biasT = (const float*)(ws + WS_BIAS);
        int cntm[4], cnti[4];
        #pragma unroll
        for (int f = 0; f < 4; ++f) cntm[f] = regcnt(16 * f + lr, hw, wwi);
        #pragma unroll
        for (int j = 0; j < 4; ++j) cnti[j] = regcnt(16 * wv + 4 * lg + j, hw, wwi);
        #pragma unroll
        for (int h = 0; h < 3; ++h) {
            #pragma unroll
            for (int f = 0; f < 4; ++f)
                #pragma unroll
                for (int j = 0; j < 4; ++j) {
                    float b = biasT[(h << 12) + (16 * wv + 4 * lg + j) * 64 + 16 * f + lr];
                    float mk = (cnti[j] != cntm[f]) ? -100.f : 0.f;
                    s[h][f][j] = fmaf(s[h][f][j], ls[h], b + mk);
                }
            #pragma unroll
            for (int j = 0; j < 4; ++j) {
                float mx = fmaxf(fmaxf(s[h][0][j], s[h][1][j]), fmaxf(s[h][2][j], s[h][3][j]));
                mx = fmaxf(mx, __shfl_xor(mx, 1)); mx = fmaxf(mx, __shfl_xor(mx, 2));
                mx = fmaxf(mx, __shfl_xor(mx, 4)); mx = fmaxf(mx, __shfl_xor(mx, 8));
                float sum = 0.f;
                #pragma unroll
                for (int f = 0; f < 4; ++f) { float e = __expf(s[h][f][j] - mx); s[h][f][j] = e; sum += e; }
                sum += __shfl_xor(sum, 1); sum += __shfl_xor(sum, 2); sum += __shfl_xor(sum, 4); sum += __shfl_xor(sum, 8);
                float inv = 1.f / sum;
                int row = 16 * wv + 4 * lg + j;
                #pragma unroll
                for (int f = 0; f < 4; ++f)
                    P[h * 64 * LDT + row * LDT + 16 * f + lr] = (bf16_t)(s[h][f][j] * inv);
            }
        }
    }
    __syncthreads();                                         // B4: P written

    // ---- phase 4: ctx = P@V, write ctxb (overlays vT) ----
    {
        bf16x8 ap[3][2], bv2[3][2][2];
        #pragma unroll
        for (int h = 0; h < 3; ++h)
            #pragma unroll
            for (int ks = 0; ks < 2; ++ks) {
                ap[h][ks] = *(const bf16x8*)(P + h * 64 * LDT + (16 * wv + lr) * LDT + 32 * ks + 8 * lg);
                #pragma unroll
                for (int dt = 0; dt < 2; ++dt)
                    bv2[h][dt][ks] = *(const bf16x8*)(vT + (32 * h + 16 * dt + lr) * LDT + 32 * ks + 8 * lg);
            }
        f32x4 ctx[6];
        #pragma unroll
        for (int t = 0; t < 6; ++t) { f32x4 z = {0.f,0.f,0.f,0.f}; ctx[t] = z; }
        #pragma unroll
        for (int h = 0; h < 3; ++h)
            #pragma unroll
            for (int ks = 0; ks < 2; ++ks)
                #pragma unroll
                for (int dt = 0; dt < 2; ++dt)
                    ctx[2 * h + dt] = mfma16(ap[h][ks], bv2[h][dt][ks], ctx[2 * h + dt]);
        __syncthreads();                                     // B5: all P/vT reads done
        #pragma unroll
        for (int t = 0; t < 6; ++t)
            #pragma unroll
            for (int j = 0; j < 4; ++j)
                ctxb[(16 * wv + 4 * lg + j) * LDC + 16 * t + lr] = (bf16_t)ctx[t][j];
    }
    __syncthreads();                                         // B6

    // ---- phase 5: proj (B from global) + conditional LN + residual -> hs ----
    {
        const bf16_t* Wp = (const bf16_t*)(ws + WS_WP);
        bf16x8 af[3];
        #pragma unroll
        for (int ks = 0; ks < 3; ++ks) af[ks] = *(const bf16x8*)(ctxb + (16 * wv + lr) * LDC + 32 * ks + 8 * lg);
        f32x4 acc[6];
        #pragma unroll
        for (int nt = 0; nt < 6; ++nt) {
            f32x4 a = {0.f,0.f,0.f,0.f};
            #pragma unroll
            for (int ks = 0; ks < 3; ++ks)
                a = mfma16(af[ks], *(const bf16x8*)(Wp + (16 * nt + lr) * LDC + 32 * ks + 8 * lg), a);
            float bp = pb[16 * nt + lr];
            #pragma unroll
            for (int j = 0; j < 4; ++j) a[j] += bp;
            acc[nt] = a;
        }
        float tb = tv[bat];
        #pragma unroll
        for (int j = 0; j < 4; ++j) {
            float smn = 0.f, sq = 0.f;
            #pragma unroll
            for (int t = 0; t < 6; ++t) { float v = acc[t][j]; smn += v; sq = fmaf(v, v, sq); }
            smn += __shfl_xor(smn, 1); smn += __shfl_xor(smn, 2); smn += __shfl_xor(smn, 4); smn += __shfl_xor(smn, 8);
            sq  += __shfl_xor(sq, 1);  sq  += __shfl_xor(sq, 2);  sq  += __shfl_xor(sq, 4);  sq  += __shfl_xor(sq, 8);
            float mean = smn * (1.f / 96.f);
            float var  = sq * (1.f / 96.f) - mean * mean;
            float rstd = rsqrtf(var + 1e-5f);
            int trow = 16 * wv + 4 * lg + j;
            int gr = ((hw << 3) + (trow >> 3) + 4) & 255;
            int gc = ((wwi << 3) + (trow & 7) + 4) & 255;
            size_t gbase = (((size_t)bat << 16) + (gr << 8) + gc) * 96;
            #pragma unroll
            for (int t = 0; t < 6; ++t) {
                int col = 16 * t + lr;
                float w = fmaf(tb, lnww[col], lnwb[col]);
                float b = fmaf(tb, lnbw[col], lnbb[col]);
                float xn = (acc[t][j] - mean) * rstd;
                hs[gbase + col] = hidden[gbase + col] + fmaf(w, xn, b);
            }
        }
    }
}

// ---------------- Kernel B: MLP + conditional LN + residual (in-place on d_out) ----------------
// LDS = gbuf only (13312) -> up to 8 blocks/CU. Weights + activations read from global.
__global__ __launch_bounds__(256, 4) void kB_mlp(
    const float* __restrict__ tv, const float* __restrict__ fc1b,
    const float* __restrict__ fc2b,
    const float* __restrict__ lnww, const float* __restrict__ lnwb,
    const float* __restrict__ lnbw, const float* __restrict__ lnbb,
    const char* __restrict__ ws, float* __restrict__ io)
{
    __shared__ __align__(16) bf16_t gbuf[64 * LDC];

    const int tid = threadIdx.x;
    const int wv = tid >> 6, lane = tid & 63, lg = lane >> 4, lr = lane & 15;
    const size_t t0 = (size_t)blockIdx.x * 64;

    // A-fragments of hs directly from global (f32 -> bf16)
    bf16x8 hf[3];
    #pragma unroll
    for (int ks = 0; ks < 3; ++ks) {
        const float* p = io + (t0 + 16 * wv + lr) * 96 + 32 * ks + 8 * lg;
        float4 u0 = *(const float4*)p;
        float4 u1 = *(const float4*)(p + 4);
        bf16x8 f;
        f[0] = (bf16_t)u0.x; f[1] = (bf16_t)u0.y; f[2] = (bf16_t)u0.z; f[3] = (bf16_t)u0.w;
        f[4] = (bf16_t)u1.x; f[5] = (bf16_t)u1.y; f[6] = (bf16_t)u1.z; f[7] = (bf16_t)u1.w;
        hf[ks] = f;
    }

    f32x4 mlp[6];
    #pragma unroll
    for (int t = 0; t < 6; ++t) { f32x4 z = {0.f,0.f,0.f,0.f}; mlp[t] = z; }
    const bf16_t* w1 = (const bf16_t*)(ws + WS_FC1);
    const bf16_t* w2 = (const bf16_t*)(ws + WS_FC2);

    for (int ch = 0; ch < 4; ++ch) {
        if (ch) __syncthreads();          // protect gbuf vs previous chunk's fc2 reads
        #pragma unroll
        for (int nt = 0; nt < 6; ++nt) {
            f32x4 a = {0.f,0.f,0.f,0.f};
            #pragma unroll
            for (int ks = 0; ks < 3; ++ks)
                a = mfma16(hf[ks], *(const bf16x8*)(w1 + (ch * 96 + 16 * nt + lr) * LDC + 32 * ks + 8 * lg), a);
            float bb = fc1b[ch * 96 + 16 * nt + lr];
            #pragma unroll
            for (int j = 0; j < 4; ++j) {
                float x = a[j] + bb;
                // tanh-form GELU: x - x/(e^{2u}+1), u = 0.79788456(x + 0.044715 x^3)
                float u = 0.7978845608f * fmaf(0.044715f * x, x * x, x);
                float t = __expf(2.f * u);
                float g = x - x * __builtin_amdgcn_rcpf(t + 1.f);
                gbuf[(16 * wv + 4 * lg + j) * LDC + 16 * nt + lr] = (bf16_t)g;
            }
        }
        __syncthreads();
        #pragma unroll
        for (int ks = 0; ks < 3; ++ks) {
            bf16x8 gf = *(const bf16x8*)(gbuf + (16 * wv + lr) * LDC + 32 * ks + 8 * lg);
            #pragma unroll
            for (int nt = 0; nt < 6; ++nt)
                mlp[nt] = mfma16(gf, *(const bf16x8*)(w2 + (ch * 96 + 16 * nt + lr) * LDC + 32 * ks + 8 * lg), mlp[nt]);
        }
    }

    float tb = tv[t0 >> 16];
    #pragma unroll
    for (int nt = 0; nt < 6; ++nt) {
        float bb = fc2b[16 * nt + lr];
        #pragma unroll
        for (int j = 0; j < 4; ++j) mlp[nt][j] += bb;
    }
    #pragma unroll
    for (int j = 0; j < 4; ++j) {
        float smn = 0.f, sq = 0.f;
        #pragma unroll
        for (int t = 0; t < 6; ++t) { float v = mlp[t][j]; smn += v; sq = fmaf(v, v, sq); }
        smn += __shfl_xor(smn, 1); smn += __shfl_xor(smn, 2); smn += __shfl_xor(smn, 4); smn += __shfl_xor(smn, 8);
        sq  += __shfl_xor(sq, 1);  sq  += __shfl_xor(sq, 2);  sq  += __shfl_xor(sq, 4);  sq  += __shfl_xor(sq, 8);
        float mean = smn * (1.f / 96.f);
        float var  = sq * (1.f / 96.f) - mean * mean;
        float rstd = rsqrtf(var + 1e-5f);
        size_t row = t0 + 16 * wv + 4 * lg + j;
        #pragma unroll
        for (int t = 0; t < 6; ++t) {
            int col = 16 * t + lr;
            float w = fmaf(tb, lnww[col], lnwb[col]);
            float b = fmaf(tb, lnbw[col], lnbb[col]);
            float xn = (mlp[t][j] - mean) * rstd;
            io[row * 96 + col] = io[row * 96 + col] + fmaf(w, xn, b);
        }
    }
}

extern "C" void kernel_launch(void* const* d_in, const int* in_sizes, int n_in,
                              void* d_out, int out_size, void* d_ws, size_t ws_size,
                              hipStream_t stream)
{
    const float* hidden = (const float*)d_in[0];
    const float* tv     = (const float*)d_in[1];
    const float* q_w    = (const float*)d_in[2];
    const float* q_b    = (const float*)d_in[3];
    const float* k_w    = (const float*)d_in[4];
    const float* v_w    = (const float*)d_in[5];
    const float* v_b    = (const float*)d_in[6];
    const float* p_w    = (const float*)d_in[7];
    const float* p_b    = (const float*)d_in[8];
    const float* lsc    = (const float*)d_in[9];
    const float* cw1    = (const float*)d_in[10];
    const float* cb1    = (const float*)d_in[11];
    const float* cw2    = (const float*)d_in[12];
    const float* lnb_ww = (const float*)d_in[13];
    const float* lnb_wb = (const float*)d_in[14];
    const float* lnb_bw = (const float*)d_in[15];
    const float* lnb_bb = (const float*)d_in[16];
    const float* lna_ww = (const float*)d_in[17];
    const float* lna_wb = (const float*)d_in[18];
    const float* lna_bw = (const float*)d_in[19];
    const float* lna_bb = (const float*)d_in[20];
    const float* fc1_b  = (const float*)d_in[22];
    const float* fc2_b  = (const float*)d_in[24];
    const float* fc1_w  = (const float*)d_in[21];
    const float* fc2_w  = (const float*)d_in[23];
    char* ws = (char*)d_ws;
    float* out = (float*)d_out;

    k0_prep<<<dim3(217), dim3(512), 0, stream>>>(q_w, k_w, v_w, p_w, fc1_w, fc2_w, cw1, cb1, cw2, ws);
    kA_attn<<<dim3(2048), dim3(256), 0, stream>>>(hidden, tv, q_b, v_b, p_b, lsc,
                                                  lnb_ww, lnb_wb, lnb_bw, lnb_bb, ws, out);
    kB_mlp<<<dim3(2048), dim3(256), 0, stream>>>(tv, fc1_b, fc2_b,
                                                 lna_ww, lna_wb, lna_bw, lna_bb, ws, out);
}